// Round 1
// baseline (684.694 us; speedup 1.0000x reference)
//
#include <hip/hip_runtime.h>
#include <stdint.h>

// Problem dims
#define NB  256
#define NT  100
#define NIN 128
#define NH  1024
#define NOUT 35

// d_out float offsets
#define O_SPK2 26214400ull
#define O_SPK3 52428800ull
#define O_SPK4 78643200ull
#define O_MEM4 79539200ull

// d_ws byte offsets
#define WS_XT   0ull          // 25600*128*4 = 13107200
#define WS_Q1T  13107200ull   // 128*1024*4  = 524288
#define WS_K2T  13631488ull   // 1048576
#define WS_K3T  14680064ull   // 1048576
#define WS_K4T  15728640ull   // 1024*48 = 49152 (padded stride 48)
#define WS_RS2  15777792ull   // 4096
#define WS_RS3  15781888ull   // 4096
#define WS_RS4  15785984ull   // 140

// scale = (w_max - w_min)/15 computed in python fp64 then cast to fp32 (matches jax weak-typing)
#define S2C ((float)((1.0 - 0.001) / 15.0))
#define S1C ((float)(1.0 / 15.0))

// ------------------------------------------------------------------
// K1: quantize weights -> transposed i8 index matrices + q1T fp32 + xt
// ------------------------------------------------------------------
__global__ void k_prep(const float* __restrict__ x, const float* __restrict__ w1,
                       const float* __restrict__ w2, const float* __restrict__ w3,
                       const float* __restrict__ w4, uint8_t* __restrict__ ws)
{
  long long id = (long long)blockIdx.x * 256 + threadIdx.x;
  if (id < 1048576) {                       // k2T[i*1024+j] = k(w2[j][i])
    int i = (int)(id >> 10), j = (int)(id & 1023);
    float wv = w2[(size_t)j * 1024 + i];
    float wc = fminf(fmaxf(wv, 0.001f), 1.0f);
    ws[WS_K2T + id] = (uint8_t)(int)rintf((wc - 0.001f) / S2C);
    return;
  }
  id -= 1048576;
  if (id < 1048576) {                       // k3T
    int i = (int)(id >> 10), j = (int)(id & 1023);
    float wv = w3[(size_t)j * 1024 + i];
    float wc = fminf(fmaxf(wv, 0.001f), 1.0f);
    ws[WS_K3T + id] = (uint8_t)(int)rintf((wc - 0.001f) / S2C);
    return;
  }
  id -= 1048576;
  if (id < 49152) {                         // k4T stride 48, pad j>=35 with 0
    int i = (int)(id / 48), j = (int)(id % 48);
    uint8_t v = 0;
    if (j < NOUT) {
      float wv = w4[(size_t)j * 1024 + i];
      float wc = fminf(fmaxf(wv, 0.001f), 1.0f);
      v = (uint8_t)(int)rintf((wc - 0.001f) / S2C);
    }
    ws[WS_K4T + id] = v;
    return;
  }
  id -= 49152;
  if (id < 131072) {                        // q1T[i*1024+j] = fake_quant(w1[j][i]) fp32
    int i = (int)(id >> 10), j = (int)(id & 1023);
    float wv = w1[(size_t)j * 128 + i];
    float wc = fminf(fmaxf(wv, -0.5f), 0.5f);
    float q = rintf((wc + 0.5f) / S1C) * S1C - 0.5f;
    ((float*)(ws + WS_Q1T))[id] = q;
    return;
  }
  id -= 131072;
  if (id < 3276800) {                       // xt[(t*256+b)*128+i] = x[b][t][i]/15
    int row = (int)(id >> 7), i = (int)(id & 127);
    int tt = row >> 8, bb = row & 255;
    ((float*)(ws + WS_XT))[id] = x[((size_t)bb * NT + tt) * NIN + i] / 15.0f;
  }
}

// ------------------------------------------------------------------
// K2: integer row-sums of k-indices (for complement-mode gathers)
// ------------------------------------------------------------------
__global__ void k_rowsum(const float* __restrict__ w2, const float* __restrict__ w3,
                         const float* __restrict__ w4, uint8_t* __restrict__ ws)
{
  int bid = blockIdx.x, tid = threadIdx.x;
  const float* W;
  uint32_t* o;
  if (bid < 1024)      { W = w2 + (size_t)bid * 1024;          o = (uint32_t*)(ws + WS_RS2) + bid; }
  else if (bid < 2048) { W = w3 + (size_t)(bid - 1024) * 1024; o = (uint32_t*)(ws + WS_RS3) + (bid - 1024); }
  else                 { W = w4 + (size_t)(bid - 2048) * 1024; o = (uint32_t*)(ws + WS_RS4) + (bid - 2048); }
  uint32_t s = 0;
  for (int i = tid; i < 1024; i += 256) {
    float wc = fminf(fmaxf(W[i], 0.001f), 1.0f);
    s += (uint32_t)(int)rintf((wc - 0.001f) / S2C);
  }
  #pragma unroll
  for (int off = 32; off; off >>= 1) s += (uint32_t)__shfl_down((int)s, off);
  __shared__ uint32_t red[4];
  if ((tid & 63) == 0) red[tid >> 6] = s;
  __syncthreads();
  if (tid == 0) *o = red[0] + red[1] + red[2] + red[3];
}

// ------------------------------------------------------------------
// K3: cur1[t*256+b][j] = dot(xt_row, q1T[:,j]) in fp32, stored into
//     the spk1 output region (consumed then overwritten by k_main).
//     Tile: 64 rows x 256 cols per block, per-thread 16x4 register tile.
// ------------------------------------------------------------------
__global__ __launch_bounds__(256) void k_cur1(const uint8_t* __restrict__ ws, float* __restrict__ out)
{
  __shared__ float xsT[128 * 68];   // [i][r], padded stride 68
  __shared__ float qch[16 * 256];   // [ii][j] chunk of q1T
  const float* xt  = (const float*)(ws + WS_XT);
  const float* q1T = (const float*)(ws + WS_Q1T);
  const int tid = threadIdx.x;
  const int rb = blockIdx.x >> 2, cb = blockIdx.x & 3;
  const int jI = tid & 63, rI = tid >> 6;
  const int j4 = jI * 4, r16 = rI * 16;

  #pragma unroll
  for (int k = 0; k < 32; ++k) {
    int e = tid + k * 256;
    int r = e >> 7, i = e & 127;
    xsT[i * 68 + r] = xt[((size_t)rb * 64 + r) * 128 + i];
  }
  float acc[16][4];
  #pragma unroll
  for (int d = 0; d < 16; ++d) {
    acc[d][0] = 0.f; acc[d][1] = 0.f; acc[d][2] = 0.f; acc[d][3] = 0.f;
  }
  for (int ic = 0; ic < 8; ++ic) {
    __syncthreads();
    #pragma unroll
    for (int k = 0; k < 16; ++k) {
      int e = tid + k * 256;
      int ii = e >> 8, j = e & 255;
      qch[ii * 256 + j] = q1T[((size_t)(ic * 16 + ii) << 10) + cb * 256 + j];
    }
    __syncthreads();
    #pragma unroll
    for (int ii = 0; ii < 16; ++ii) {
      int i = ic * 16 + ii;
      const float4 q  = *(const float4*)&qch[ii * 256 + j4];
      const float4 xa = *(const float4*)&xsT[i * 68 + r16];
      const float4 xb = *(const float4*)&xsT[i * 68 + r16 + 4];
      const float4 xc = *(const float4*)&xsT[i * 68 + r16 + 8];
      const float4 xd = *(const float4*)&xsT[i * 68 + r16 + 12];
      float xr[16];
      xr[0]=xa.x; xr[1]=xa.y; xr[2]=xa.z; xr[3]=xa.w;
      xr[4]=xb.x; xr[5]=xb.y; xr[6]=xb.z; xr[7]=xb.w;
      xr[8]=xc.x; xr[9]=xc.y; xr[10]=xc.z; xr[11]=xc.w;
      xr[12]=xd.x; xr[13]=xd.y; xr[14]=xd.z; xr[15]=xd.w;
      #pragma unroll
      for (int d = 0; d < 16; ++d) {
        acc[d][0] = fmaf(xr[d], q.x, acc[d][0]);
        acc[d][1] = fmaf(xr[d], q.y, acc[d][1]);
        acc[d][2] = fmaf(xr[d], q.z, acc[d][2]);
        acc[d][3] = fmaf(xr[d], q.w, acc[d][3]);
      }
    }
  }
  #pragma unroll
  for (int d = 0; d < 16; ++d) {
    float4 v = make_float4(acc[d][0], acc[d][1], acc[d][2], acc[d][3]);
    *(float4*)&out[((size_t)rb * 64 + r16 + d) * 1024 + cb * 256 + j4] = v;
  }
}

// ------------------------------------------------------------------
// K4: persistent per-batch-element SNN loop. One block per batch elem.
//     Exact integer gathers over active (or complement) spike lists.
// ------------------------------------------------------------------
__global__ __launch_bounds__(512) void k_main(const uint8_t* __restrict__ ws, float* out)
{
  const int b = blockIdx.x;
  const int tid = threadIdx.x;
  const int lane = tid & 63;
  const int wave = tid >> 6;       // 8 waves = 8 gather groups
  const int g8 = wave;
  const int n64 = lane;            // 16 neurons per thread in gathers

  const uint8_t* k2T = ws + WS_K2T;
  const uint8_t* k3T = ws + WS_K3T;
  const uint8_t* k4T = ws + WS_K4T;
  const uint32_t* rs2 = (const uint32_t*)(ws + WS_RS2);
  const uint32_t* rs3 = (const uint32_t*)(ws + WS_RS3);
  const uint32_t* rs4 = (const uint32_t*)(ws + WS_RS4);

  __shared__ uint16_t list[1024];
  __shared__ uint32_t pEa[2048];   // [g][word] packed u16 sums (neurons 0,2 of each quad)
  __shared__ uint32_t pOa[2048];   // neurons 1,3
  __shared__ uint32_t wcnt[8];
  __shared__ uint32_t lpos;

  float m1[2] = {0.f, 0.f}, m2[2] = {0.f, 0.f}, m3[2] = {0.f, 0.f}, m4 = 0.f;
  uint32_t r2[2], r3[2], r4v = 0;
  r2[0] = rs2[tid]; r2[1] = rs2[tid + 512];
  r3[0] = rs3[tid]; r3[1] = rs3[tid + 512];
  if (tid < NOUT) r4v = rs4[tid];

  uint32_t nT, nL; bool cm;
  auto buildList = [&](bool sA, bool sB) {
    if (tid == 0) lpos = 0;
    uint64_t bA = __ballot(sA), bB = __ballot(sB);
    if (lane == 0) wcnt[wave] = (uint32_t)(__popcll(bA) + __popcll(bB));
    __syncthreads();
    nT = wcnt[0]+wcnt[1]+wcnt[2]+wcnt[3]+wcnt[4]+wcnt[5]+wcnt[6]+wcnt[7];
    cm = nT > 512;
    nL = cm ? (1024u - nT) : nT;
    uint64_t cA = cm ? ~bA : bA;
    uint64_t cB = cm ? ~bB : bB;
    uint32_t cnt = (uint32_t)(__popcll(cA) + __popcll(cB));
    uint32_t bs = 0;
    if (lane == 0) bs = atomicAdd(&lpos, cnt);
    bs = (uint32_t)__shfl((int)bs, 0);
    uint64_t ltm = (1ull << lane) - 1ull;
    if ((cA >> lane) & 1ull) list[bs + (uint32_t)__popcll(cA & ltm)] = (uint16_t)tid;
    if ((cB >> lane) & 1ull) list[bs + (uint32_t)__popcll(cA) + (uint32_t)__popcll(cB & ltm)] = (uint16_t)(tid + 512);
    __syncthreads();
  };

  auto gatherBig = [&](const uint8_t* mat) {  // stride-1024 matrices, all 512 threads
    uint32_t aE0=0,aE1=0,aE2=0,aE3=0,aO0=0,aO1=0,aO2=0,aO3=0;
    const uint8_t* bp = mat + (n64 << 4);
    for (uint32_t a = (uint32_t)g8; a < nL; a += 8) {
      uint32_t idx = list[a];
      const uint4 w = *(const uint4*)(bp + ((size_t)idx << 10));
      aE0 += w.x & 0x00FF00FFu; aO0 += (w.x >> 8) & 0x00FF00FFu;
      aE1 += w.y & 0x00FF00FFu; aO1 += (w.y >> 8) & 0x00FF00FFu;
      aE2 += w.z & 0x00FF00FFu; aO2 += (w.z >> 8) & 0x00FF00FFu;
      aE3 += w.w & 0x00FF00FFu; aO3 += (w.w >> 8) & 0x00FF00FFu;
    }
    int basei = (g8 << 8) + (n64 << 2);
    pEa[basei+0]=aE0; pEa[basei+1]=aE1; pEa[basei+2]=aE2; pEa[basei+3]=aE3;
    pOa[basei+0]=aO0; pOa[basei+1]=aO1; pOa[basei+2]=aO2; pOa[basei+3]=aO3;
  };

  auto gsum = [&](int j) -> uint32_t {
    int w = j >> 2;
    int sh = (j & 2) << 3;
    const uint32_t* P = (j & 1) ? pOa : pEa;
    uint32_t s = 0;
    #pragma unroll
    for (int gg = 0; gg < 8; ++gg) s += (P[(gg << 8) + w] >> sh) & 0xffffu;
    return s;
  };

  float curN[2];
  {
    size_t row0 = (size_t)b * NH;
    curN[0] = out[row0 + tid];
    curN[1] = out[row0 + tid + 512];
  }

  for (int t = 0; t < NT; ++t) {
    const size_t rowH = ((size_t)t * NB + b) * (size_t)NH;
    const size_t rowO = ((size_t)t * NB + b) * (size_t)NOUT;
    bool sA, sB;
    // ---- layer 1 (cur precomputed; in-place spk1 overwrite) ----
    {
      float c0 = curN[0], c1 = curN[1];
      int tn = (t + 1 < NT) ? (t + 1) : t;
      size_t rowN = ((size_t)tn * NB + b) * (size_t)NH;
      curN[0] = out[rowN + tid];          // prefetch next step
      curN[1] = out[rowN + tid + 512];
      float rst0 = m1[0] > 1.0f ? 1.0f : 0.0f;
      m1[0] = fmaf(0.9f, m1[0], c0) - rst0;
      sA = (m1[0] - 1.0f) > 0.0f;
      out[rowH + tid] = sA ? 1.0f : 0.0f;
      float rst1 = m1[1] > 1.0f ? 1.0f : 0.0f;
      m1[1] = fmaf(0.9f, m1[1], c1) - rst1;
      sB = (m1[1] - 1.0f) > 0.0f;
      out[rowH + tid + 512] = sB ? 1.0f : 0.0f;
    }
    buildList(sA, sB);
    uint32_t n1 = nT, nl1 = nL; bool cm1 = cm;
    if (nl1) gatherBig(k2T);
    __syncthreads();
    // ---- layer 2 ----
    {
      float nb = 0.001f * (float)n1;
      #pragma unroll
      for (int c = 0; c < 2; ++c) {
        int j = (c << 9) + tid;
        uint32_t gsv = nl1 ? gsum(j) : 0u;
        uint32_t K = cm1 ? (r2[c] - gsv) : gsv;
        float cur = fmaf(S2C, (float)K, nb);
        float rst = m2[c] > 1.0f ? 1.0f : 0.0f;
        m2[c] = fmaf(0.85f, m2[c], cur) - rst;
        bool sp = (m2[c] - 1.0f) > 0.0f;
        out[O_SPK2 + rowH + j] = sp ? 1.0f : 0.0f;
        if (c == 0) sA = sp; else sB = sp;
      }
    }
    buildList(sA, sB);
    uint32_t n2 = nT, nl2 = nL; bool cm2 = cm;
    if (nl2) gatherBig(k3T);
    __syncthreads();
    // ---- layer 3 ----
    {
      float nb = 0.001f * (float)n2;
      #pragma unroll
      for (int c = 0; c < 2; ++c) {
        int j = (c << 9) + tid;
        uint32_t gsv = nl2 ? gsum(j) : 0u;
        uint32_t K = cm2 ? (r3[c] - gsv) : gsv;
        float cur = fmaf(S2C, (float)K, nb);
        float rst = m3[c] > 1.0f ? 1.0f : 0.0f;
        m3[c] = fmaf(0.8f, m3[c], cur) - rst;
        bool sp = (m3[c] - 1.0f) > 0.0f;
        out[O_SPK3 + rowH + j] = sp ? 1.0f : 0.0f;
        if (c == 0) sA = sp; else sB = sp;
      }
    }
    buildList(sA, sB);
    uint32_t n3 = nT, nl3 = nL; bool cm3 = cm;
    // ---- layer 4 gather (48 padded cols; groups' threads n64<3) ----
    if (nl3 && n64 < 3) {
      uint32_t aE0=0,aE1=0,aE2=0,aE3=0,aO0=0,aO1=0,aO2=0,aO3=0;
      const uint8_t* bp = k4T + (n64 << 4);
      for (uint32_t a = (uint32_t)g8; a < nl3; a += 8) {
        uint32_t idx = list[a];
        const uint4 w = *(const uint4*)(bp + (size_t)idx * 48);
        aE0 += w.x & 0x00FF00FFu; aO0 += (w.x >> 8) & 0x00FF00FFu;
        aE1 += w.y & 0x00FF00FFu; aO1 += (w.y >> 8) & 0x00FF00FFu;
        aE2 += w.z & 0x00FF00FFu; aO2 += (w.z >> 8) & 0x00FF00FFu;
        aE3 += w.w & 0x00FF00FFu; aO3 += (w.w >> 8) & 0x00FF00FFu;
      }
      int basei = (g8 << 8) + (n64 << 2);
      pEa[basei+0]=aE0; pEa[basei+1]=aE1; pEa[basei+2]=aE2; pEa[basei+3]=aE3;
      pOa[basei+0]=aO0; pOa[basei+1]=aO1; pOa[basei+2]=aO2; pOa[basei+3]=aO3;
    }
    __syncthreads();
    // ---- layer 4 membrane (reset-to-zero) ----
    if (tid < NOUT) {
      uint32_t gsv = nl3 ? gsum(tid) : 0u;
      uint32_t K = cm3 ? (r4v - gsv) : gsv;
      float cur = fmaf(S2C, (float)K, 0.001f * (float)n3);
      float rst = m4 > 1.0f ? 1.0f : 0.0f;
      float bsv = fmaf(0.95f, m4, cur);
      m4 = (rst > 0.0f) ? 0.0f : bsv;
      out[O_SPK4 + rowO + tid] = ((m4 - 1.0f) > 0.0f) ? 1.0f : 0.0f;
      out[O_MEM4 + rowO + tid] = m4;
    }
  }
}

extern "C" void kernel_launch(void* const* d_in, const int* in_sizes, int n_in,
                              void* d_out, int out_size, void* d_ws, size_t ws_size,
                              hipStream_t stream)
{
  const float* x  = (const float*)d_in[0];
  const float* w1 = (const float*)d_in[1];
  const float* w2 = (const float*)d_in[2];
  const float* w3 = (const float*)d_in[3];
  const float* w4 = (const float*)d_in[4];
  float* out = (float*)d_out;
  uint8_t* ws = (uint8_t*)d_ws;
  hipLaunchKernelGGL(k_prep,   dim3(21696), dim3(256), 0, stream, x, w1, w2, w3, w4, ws);
  hipLaunchKernelGGL(k_rowsum, dim3(2083),  dim3(256), 0, stream, w2, w3, w4, ws);
  hipLaunchKernelGGL(k_cur1,   dim3(1600),  dim3(256), 0, stream, ws, out);
  hipLaunchKernelGGL(k_main,   dim3(256),   dim3(512), 0, stream, ws, out);
}